// Round 1
// baseline (1399.256 us; speedup 1.0000x reference)
//
#include <hip/hip_runtime.h>

#define N_NODES 100000
#define D_SRC 128
#define D_OUT 256
#define K_DIM 256   // D_DST + D_SRC

// ---------------------------------------------------------------------------
// Kernel 1: scatter-add of x_src rows into agg[dst] + count[dst].
// 32 lanes per edge, each lane handles one float4 (128 floats per row).
// ---------------------------------------------------------------------------
__global__ __launch_bounds__(256) void scatter_add_kernel(
    const float* __restrict__ x_src,   // [N, 128]
    const int*   __restrict__ ei,      // [2, E] (src row then dst row)
    float*       __restrict__ agg,     // [N, 128] (pre-zeroed)
    float*       __restrict__ cnt,     // [N]      (pre-zeroed)
    int n_edges)
{
    int lane = threadIdx.x & 31;
    int e = blockIdx.x * (blockDim.x >> 5) + (threadIdx.x >> 5);
    if (e >= n_edges) return;
    int s = ei[e];
    int d = ei[n_edges + e];
    float4 v = ((const float4*)(x_src + (size_t)s * D_SRC))[lane];
    float* a = agg + (size_t)d * D_SRC + lane * 4;
    unsafeAtomicAdd(a + 0, v.x);
    unsafeAtomicAdd(a + 1, v.y);
    unsafeAtomicAdd(a + 2, v.z);
    unsafeAtomicAdd(a + 3, v.w);
    if (lane == 0) unsafeAtomicAdd(cnt + d, 1.0f);
}

// ---------------------------------------------------------------------------
// Kernel 2: fused  out = relu([x_dst | agg/max(cnt,1)] @ W^T + b)
// Tile: BM=64 x BN=64, BK=32. 256 threads, 4x4 micro-tile each.
// LDS holds transposed h-tile and W-tile so inner loop reads are b128.
// ---------------------------------------------------------------------------
#define BM 64
#define BN 64
#define BK 32

__global__ __launch_bounds__(256) void fused_gemm_kernel(
    const float* __restrict__ x_dst,   // [N, 128]
    const float* __restrict__ agg,     // [N, 128] (sums)
    const float* __restrict__ cnt,     // [N]
    const float* __restrict__ W,       // [256, 256] row-major [out][in]
    const float* __restrict__ bias,    // [256]
    float*       __restrict__ out)     // [N, 256]
{
    __shared__ float hsT[BK][BM];   // hsT[k][m]
    __shared__ float wsT[BK][BN];   // wsT[k][n]
    __shared__ float inv_s[BM];

    int t  = threadIdx.x;
    int tx = t & 15;    // n-quad selector (n = tx*4 .. +3)
    int ty = t >> 4;    // m-quad selector (m = ty*4 .. +3)
    int m0 = blockIdx.x * BM;
    int n0 = blockIdx.y * BN;

    if (t < BM) {
        int m = m0 + t;
        float c = (m < N_NODES) ? cnt[m] : 1.0f;
        inv_s[t] = 1.0f / fmaxf(c, 1.0f);
    }
    __syncthreads();

    float acc[4][4] = {};

    for (int kc = 0; kc < K_DIM / BK; ++kc) {
        int k0 = kc * BK;

        // ---- stage W chunk (transposed): wsT[k][n] = W[n0+n][k0+k] ----
        #pragma unroll
        for (int r = 0; r < 2; ++r) {
            int i  = t + r * 256;
            int n  = i >> 3;            // 0..63
            int k4 = (i & 7) << 2;      // 0,4,...,28
            float4 w4 = *(const float4*)(W + (size_t)(n0 + n) * K_DIM + k0 + k4);
            wsT[k4 + 0][n] = w4.x;
            wsT[k4 + 1][n] = w4.y;
            wsT[k4 + 2][n] = w4.z;
            wsT[k4 + 3][n] = w4.w;
        }

        // ---- stage h chunk (transposed): hsT[k][m] = h[m0+m][k0+k] ----
        {
            bool is_agg = (k0 >= 128);
            const float* src = is_agg ? agg : x_dst;
            int koff = is_agg ? (k0 - 128) : k0;
            #pragma unroll
            for (int r = 0; r < 2; ++r) {
                int i  = t + r * 256;
                int m  = i >> 3;
                int k4 = (i & 7) << 2;
                int row = m0 + m;
                float4 v4 = make_float4(0.f, 0.f, 0.f, 0.f);
                if (row < N_NODES)
                    v4 = *(const float4*)(src + (size_t)row * D_SRC + koff + k4);
                if (is_agg) {
                    float iv = inv_s[m];
                    v4.x *= iv; v4.y *= iv; v4.z *= iv; v4.w *= iv;
                }
                hsT[k4 + 0][m] = v4.x;
                hsT[k4 + 1][m] = v4.y;
                hsT[k4 + 2][m] = v4.z;
                hsT[k4 + 3][m] = v4.w;
            }
        }
        __syncthreads();

        // ---- inner product: 2 x ds_read_b128 + 16 FMA per k ----
        #pragma unroll
        for (int kk = 0; kk < BK; ++kk) {
            float4 hv4 = *(const float4*)(&hsT[kk][ty * 4]);
            float4 wv4 = *(const float4*)(&wsT[kk][tx * 4]);
            const float* hv = (const float*)&hv4;
            const float* wv = (const float*)&wv4;
            #pragma unroll
            for (int im = 0; im < 4; ++im)
                #pragma unroll
                for (int in = 0; in < 4; ++in)
                    acc[im][in] += hv[im] * wv[in];
        }
        __syncthreads();
    }

    // ---- epilogue: bias + relu + store ----
    float4 b4 = *(const float4*)(bias + n0 + tx * 4);
    const float* bb = (const float*)&b4;
    #pragma unroll
    for (int im = 0; im < 4; ++im) {
        int row = m0 + ty * 4 + im;
        if (row < N_NODES) {
            float4 o;
            o.x = fmaxf(acc[im][0] + bb[0], 0.f);
            o.y = fmaxf(acc[im][1] + bb[1], 0.f);
            o.z = fmaxf(acc[im][2] + bb[2], 0.f);
            o.w = fmaxf(acc[im][3] + bb[3], 0.f);
            *(float4*)(out + (size_t)row * D_OUT + n0 + tx * 4) = o;
        }
    }
}

extern "C" void kernel_launch(void* const* d_in, const int* in_sizes, int n_in,
                              void* d_out, int out_size, void* d_ws, size_t ws_size,
                              hipStream_t stream) {
    const float* x_src = (const float*)d_in[0];
    const float* x_dst = (const float*)d_in[1];
    const int*   ei    = (const int*)d_in[2];
    const float* W     = (const float*)d_in[3];
    const float* bias  = (const float*)d_in[4];
    float* out = (float*)d_out;

    int n_edges = in_sizes[2] / 2;

    // workspace layout: agg [N_NODES*128] f32, cnt [N_NODES] f32
    float* agg = (float*)d_ws;
    float* cnt = agg + (size_t)N_NODES * D_SRC;
    size_t zero_bytes = ((size_t)N_NODES * D_SRC + N_NODES) * sizeof(float);
    hipMemsetAsync(d_ws, 0, zero_bytes, stream);

    // scatter: 8 edges per 256-thread block
    int sblocks = (n_edges + 7) / 8;
    scatter_add_kernel<<<sblocks, 256, 0, stream>>>(x_src, ei, agg, cnt, n_edges);

    // fused mean + GEMM + bias + relu
    dim3 grid((N_NODES + BM - 1) / BM, D_OUT / BN);
    fused_gemm_kernel<<<grid, 256, 0, stream>>>(x_dst, agg, cnt, W, bias, out);
}

// Round 2
// 455.985 us; speedup vs baseline: 3.0686x; 3.0686x over previous
//
#include <hip/hip_runtime.h>

#define N_NODES 100000
#define D_SRC 128
#define D_OUT 256
#define K_DIM 256   // D_DST + D_SRC
#define CAP 32      // bucket capacity per node (Poisson(6): P(deg>32) ~ 1e-15)
#define OVF_CAP 2048

// ---------------------------------------------------------------------------
// Kernel 1: bucket edges by dst. deg[d] counts ALL edges; first CAP edge
// sources land in bucket[d*CAP + pos]; the (astronomically rare) rest go to
// the overflow list.
// ---------------------------------------------------------------------------
__global__ __launch_bounds__(256) void bucket_kernel(
    const int* __restrict__ ei,     // [2, E]
    int* __restrict__ deg,          // [N] (pre-zeroed)
    int* __restrict__ ovf_cnt,      // [1] (pre-zeroed)
    int* __restrict__ ovf,          // [OVF_CAP*2]
    int* __restrict__ bucket,       // [N*CAP]
    int n_edges)
{
    int e = blockIdx.x * 256 + threadIdx.x;
    if (e >= n_edges) return;
    int s = ei[e];
    int d = ei[n_edges + e];
    int pos = atomicAdd(deg + d, 1);
    if (pos < CAP) {
        bucket[(size_t)d * CAP + pos] = s;
    } else {
        int o = atomicAdd(ovf_cnt, 1);
        if (o < OVF_CAP) { ovf[2 * o] = s; ovf[2 * o + 1] = d; }
    }
}

// ---------------------------------------------------------------------------
// Kernel 2: gather-sum. One 64-lane wave per dst node; lane owns a float2
// column slice. Edge indices preloaded into a register, __shfl-broadcast.
// Writes agg (sum) exactly once per node — no atomics.
// ---------------------------------------------------------------------------
__global__ __launch_bounds__(256) void gather_kernel(
    const float* __restrict__ x_src,   // [N, 128]
    const int*   __restrict__ deg,     // [N]
    const int*   __restrict__ bucket,  // [N*CAP]
    float*       __restrict__ agg)     // [N, 128] (sums, fully overwritten)
{
    int node = blockIdx.x * 4 + (threadIdx.x >> 6);
    if (node >= N_NODES) return;
    int lane = threadIdx.x & 63;

    int n = deg[node];
    n = (n < CAP) ? n : CAP;

    // preload up to 32 edge sources into one register (lanes 0..31 valid)
    int idx = bucket[(size_t)node * CAP + (lane & 31)];

    float2 acc0 = make_float2(0.f, 0.f);
    float2 acc1 = make_float2(0.f, 0.f);
    int i = 0;
    for (; i + 2 <= n; i += 2) {
        int s0 = __shfl(idx, i);
        int s1 = __shfl(idx, i + 1);
        float2 v0 = *(const float2*)(x_src + (size_t)s0 * D_SRC + lane * 2);
        float2 v1 = *(const float2*)(x_src + (size_t)s1 * D_SRC + lane * 2);
        acc0.x += v0.x; acc0.y += v0.y;
        acc1.x += v1.x; acc1.y += v1.y;
    }
    if (i < n) {
        int s0 = __shfl(idx, i);
        float2 v0 = *(const float2*)(x_src + (size_t)s0 * D_SRC + lane * 2);
        acc0.x += v0.x; acc0.y += v0.y;
    }
    acc0.x += acc1.x; acc0.y += acc1.y;
    *(float2*)(agg + (size_t)node * D_SRC + lane * 2) = acc0;
}

// ---------------------------------------------------------------------------
// Kernel 3: overflow fixup (expected 0 iterations). Atomic-adds the rare
// overflow edges into agg. Fixed grid; count read from device memory.
// ---------------------------------------------------------------------------
__global__ __launch_bounds__(256) void ovf_fixup_kernel(
    const float* __restrict__ x_src,
    const int* __restrict__ ovf_cnt,
    const int* __restrict__ ovf,
    float* __restrict__ agg)
{
    int e = blockIdx.x * 8 + (threadIdx.x >> 5);
    int lane = threadIdx.x & 31;
    int n = *ovf_cnt;
    if (n > OVF_CAP) n = OVF_CAP;
    if (e >= n) return;
    int s = ovf[2 * e];
    int d = ovf[2 * e + 1];
    float4 v = ((const float4*)(x_src + (size_t)s * D_SRC))[lane];
    float* a = agg + (size_t)d * D_SRC + lane * 4;
    unsafeAtomicAdd(a + 0, v.x);
    unsafeAtomicAdd(a + 1, v.y);
    unsafeAtomicAdd(a + 2, v.z);
    unsafeAtomicAdd(a + 3, v.w);
}

// ---------------------------------------------------------------------------
// Kernel 4: fused  out = relu([x_dst | agg/max(deg,1)] @ W^T + b)
// Tile: BM=64 x BN=64, BK=32. 256 threads, 4x4 micro-tile each.
// ---------------------------------------------------------------------------
#define BM 64
#define BN 64
#define BK 32

__global__ __launch_bounds__(256) void fused_gemm_kernel(
    const float* __restrict__ x_dst,   // [N, 128]
    const float* __restrict__ agg,     // [N, 128] (sums)
    const int*   __restrict__ deg,     // [N]
    const float* __restrict__ W,       // [256, 256] row-major [out][in]
    const float* __restrict__ bias,    // [256]
    float*       __restrict__ out)     // [N, 256]
{
    __shared__ float hsT[BK][BM];   // hsT[k][m]
    __shared__ float wsT[BK][BN];   // wsT[k][n]
    __shared__ float inv_s[BM];

    int t  = threadIdx.x;
    int tx = t & 15;    // n-quad selector (n = tx*4 .. +3)
    int ty = t >> 4;    // m-quad selector (m = ty*4 .. +3)
    int m0 = blockIdx.x * BM;
    int n0 = blockIdx.y * BN;

    if (t < BM) {
        int m = m0 + t;
        int c = (m < N_NODES) ? deg[m] : 1;
        inv_s[t] = 1.0f / (float)((c > 1) ? c : 1);
    }
    __syncthreads();

    float acc[4][4] = {};

    for (int kc = 0; kc < K_DIM / BK; ++kc) {
        int k0 = kc * BK;

        // ---- stage W chunk (transposed): wsT[k][n] = W[n0+n][k0+k] ----
        #pragma unroll
        for (int r = 0; r < 2; ++r) {
            int i  = t + r * 256;
            int n  = i >> 3;            // 0..63
            int k4 = (i & 7) << 2;      // 0,4,...,28
            float4 w4 = *(const float4*)(W + (size_t)(n0 + n) * K_DIM + k0 + k4);
            wsT[k4 + 0][n] = w4.x;
            wsT[k4 + 1][n] = w4.y;
            wsT[k4 + 2][n] = w4.z;
            wsT[k4 + 3][n] = w4.w;
        }

        // ---- stage h chunk (transposed): hsT[k][m] = h[m0+m][k0+k] ----
        {
            bool is_agg = (k0 >= 128);
            const float* src = is_agg ? agg : x_dst;
            int koff = is_agg ? (k0 - 128) : k0;
            #pragma unroll
            for (int r = 0; r < 2; ++r) {
                int i  = t + r * 256;
                int m  = i >> 3;
                int k4 = (i & 7) << 2;
                int row = m0 + m;
                float4 v4 = make_float4(0.f, 0.f, 0.f, 0.f);
                if (row < N_NODES)
                    v4 = *(const float4*)(src + (size_t)row * D_SRC + koff + k4);
                if (is_agg) {
                    float iv = inv_s[m];
                    v4.x *= iv; v4.y *= iv; v4.z *= iv; v4.w *= iv;
                }
                hsT[k4 + 0][m] = v4.x;
                hsT[k4 + 1][m] = v4.y;
                hsT[k4 + 2][m] = v4.z;
                hsT[k4 + 3][m] = v4.w;
            }
        }
        __syncthreads();

        // ---- inner product: 2 x ds_read_b128 + 16 FMA per k ----
        #pragma unroll
        for (int kk = 0; kk < BK; ++kk) {
            float4 hv4 = *(const float4*)(&hsT[kk][ty * 4]);
            float4 wv4 = *(const float4*)(&wsT[kk][tx * 4]);
            const float* hv = (const float*)&hv4;
            const float* wv = (const float*)&wv4;
            #pragma unroll
            for (int im = 0; im < 4; ++im)
                #pragma unroll
                for (int in = 0; in < 4; ++in)
                    acc[im][in] += hv[im] * wv[in];
        }
        __syncthreads();
    }

    // ---- epilogue: bias + relu + store ----
    float4 b4 = *(const float4*)(bias + n0 + tx * 4);
    const float* bb = (const float*)&b4;
    #pragma unroll
    for (int im = 0; im < 4; ++im) {
        int row = m0 + ty * 4 + im;
        if (row < N_NODES) {
            float4 o;
            o.x = fmaxf(acc[im][0] + bb[0], 0.f);
            o.y = fmaxf(acc[im][1] + bb[1], 0.f);
            o.z = fmaxf(acc[im][2] + bb[2], 0.f);
            o.w = fmaxf(acc[im][3] + bb[3], 0.f);
            *(float4*)(out + (size_t)row * D_OUT + n0 + tx * 4) = o;
        }
    }
}

extern "C" void kernel_launch(void* const* d_in, const int* in_sizes, int n_in,
                              void* d_out, int out_size, void* d_ws, size_t ws_size,
                              hipStream_t stream) {
    const float* x_src = (const float*)d_in[0];
    const float* x_dst = (const float*)d_in[1];
    const int*   ei    = (const int*)d_in[2];
    const float* W     = (const float*)d_in[3];
    const float* bias  = (const float*)d_in[4];
    float* out = (float*)d_out;

    int n_edges = in_sizes[2] / 2;

    // workspace layout (bytes):
    //   deg     : N_NODES int            (zeroed)
    //   ovf_cnt : 1 int + 3 pad          (zeroed)
    //   ovf     : OVF_CAP*2 int
    //   bucket  : N_NODES*CAP int
    //   agg     : N_NODES*128 float
    int* deg     = (int*)d_ws;
    int* ovf_cnt = deg + N_NODES;
    int* ovf     = ovf_cnt + 4;
    int* bucket  = ovf + OVF_CAP * 2;
    float* agg   = (float*)(bucket + (size_t)N_NODES * CAP);

    hipMemsetAsync(d_ws, 0, (N_NODES + 4) * sizeof(int), stream);

    bucket_kernel<<<(n_edges + 255) / 256, 256, 0, stream>>>(
        ei, deg, ovf_cnt, ovf, bucket, n_edges);

    gather_kernel<<<(N_NODES + 3) / 4, 256, 0, stream>>>(
        x_src, deg, bucket, agg);

    ovf_fixup_kernel<<<OVF_CAP / 8, 256, 0, stream>>>(
        x_src, ovf_cnt, ovf, agg);

    dim3 grid((N_NODES + BM - 1) / BM, D_OUT / BN);
    fused_gemm_kernel<<<grid, 256, 0, stream>>>(x_dst, agg, deg, W, bias, out);
}

// Round 3
// 344.034 us; speedup vs baseline: 4.0672x; 1.3254x over previous
//
#include <hip/hip_runtime.h>

#define N_NODES 100000
#define D_SRC 128
#define D_OUT 256
#define K_DIM 256   // D_DST + D_SRC
#define CAP 32      // bucket capacity per node (Poisson(6): P(deg>32) ~ 1e-15)
#define OVF_CAP 2048

typedef __attribute__((ext_vector_type(8))) short short8;
typedef __attribute__((ext_vector_type(4))) float float4v;

__device__ inline unsigned short f2bf(float f) {
    unsigned int u = __float_as_uint(f);
    u += 0x7FFF + ((u >> 16) & 1);   // round-to-nearest-even
    return (unsigned short)(u >> 16);
}

// ---------------------------------------------------------------------------
// Kernel 1: bucket edges by dst.
// ---------------------------------------------------------------------------
__global__ __launch_bounds__(256) void bucket_kernel(
    const int* __restrict__ ei,     // [2, E]
    int* __restrict__ deg,          // [N] (pre-zeroed)
    int* __restrict__ ovf_cnt,      // [1] (pre-zeroed)
    int* __restrict__ ovf,          // [OVF_CAP*2]
    int* __restrict__ bucket,       // [N*CAP]
    int n_edges)
{
    int e = blockIdx.x * 256 + threadIdx.x;
    if (e >= n_edges) return;
    int s = ei[e];
    int d = ei[n_edges + e];
    int pos = atomicAdd(deg + d, 1);
    if (pos < CAP) {
        bucket[(size_t)d * CAP + pos] = s;
    } else {
        int o = atomicAdd(ovf_cnt, 1);
        if (o < OVF_CAP) { ovf[2 * o] = s; ovf[2 * o + 1] = d; }
    }
}

// ---------------------------------------------------------------------------
// Kernel 2: gather-sum into fp32 agg. One 64-lane wave per node.
// ---------------------------------------------------------------------------
__global__ __launch_bounds__(256) void gather_kernel(
    const float* __restrict__ x_src,   // [N, 128]
    const int*   __restrict__ deg,     // [N]
    const int*   __restrict__ bucket,  // [N*CAP]
    float*       __restrict__ agg)     // [N, 128] (sums, fully overwritten)
{
    int node = blockIdx.x * 4 + (threadIdx.x >> 6);
    if (node >= N_NODES) return;
    int lane = threadIdx.x & 63;

    int n = deg[node];
    n = (n < CAP) ? n : CAP;

    int idx = bucket[(size_t)node * CAP + (lane & 31)];

    float2 acc0 = make_float2(0.f, 0.f);
    float2 acc1 = make_float2(0.f, 0.f);
    int i = 0;
    for (; i + 2 <= n; i += 2) {
        int s0 = __shfl(idx, i);
        int s1 = __shfl(idx, i + 1);
        float2 v0 = *(const float2*)(x_src + (size_t)s0 * D_SRC + lane * 2);
        float2 v1 = *(const float2*)(x_src + (size_t)s1 * D_SRC + lane * 2);
        acc0.x += v0.x; acc0.y += v0.y;
        acc1.x += v1.x; acc1.y += v1.y;
    }
    if (i < n) {
        int s0 = __shfl(idx, i);
        float2 v0 = *(const float2*)(x_src + (size_t)s0 * D_SRC + lane * 2);
        acc0.x += v0.x; acc0.y += v0.y;
    }
    acc0.x += acc1.x; acc0.y += acc1.y;
    *(float2*)(agg + (size_t)node * D_SRC + lane * 2) = acc0;
}

// ---------------------------------------------------------------------------
// Kernel 3: overflow fixup (expected 0 iterations).
// ---------------------------------------------------------------------------
__global__ __launch_bounds__(256) void ovf_fixup_kernel(
    const float* __restrict__ x_src,
    const int* __restrict__ ovf_cnt,
    const int* __restrict__ ovf,
    float* __restrict__ agg)
{
    int e = blockIdx.x * 8 + (threadIdx.x >> 5);
    int lane = threadIdx.x & 31;
    int n = *ovf_cnt;
    if (n > OVF_CAP) n = OVF_CAP;
    if (e >= n) return;
    int s = ovf[2 * e];
    int d = ovf[2 * e + 1];
    float4 v = ((const float4*)(x_src + (size_t)s * D_SRC))[lane];
    float* a = agg + (size_t)d * D_SRC + lane * 4;
    unsafeAtomicAdd(a + 0, v.x);
    unsafeAtomicAdd(a + 1, v.y);
    unsafeAtomicAdd(a + 2, v.z);
    unsafeAtomicAdd(a + 3, v.w);
}

// ---------------------------------------------------------------------------
// Kernel 4: W fp32 -> bf16 (once per launch, 65536 elements)
// ---------------------------------------------------------------------------
__global__ __launch_bounds__(256) void convert_w_kernel(
    const float* __restrict__ W, unsigned short* __restrict__ Wb)
{
    int i = blockIdx.x * 256 + threadIdx.x;   // 16384 float4s
    float4 v = ((const float4*)W)[i];
    ushort4 o;
    o.x = f2bf(v.x); o.y = f2bf(v.y); o.z = f2bf(v.z); o.w = f2bf(v.w);
    ((ushort4*)Wb)[i] = o;
}

// ---------------------------------------------------------------------------
// Kernel 5: bf16-MFMA fused  out = relu([x_dst | agg/max(deg,1)] @ W^T + b)
// BM=128, BN=256 (full N), BK=32. 512 threads = 8 waves, each 64x64.
// A staged fp32->bf16 in-register; B from pre-converted Wb.
// ---------------------------------------------------------------------------
#define BM 128
#define BK 32
#define PADK 40   // LDS row stride in bf16 elements (80B: breaks pow2 banks, 16B-aligned)

__global__ __launch_bounds__(512) void mfma_gemm_kernel(
    const float* __restrict__ x_dst,          // [N, 128]
    const float* __restrict__ agg,            // [N, 128] (sums)
    const int*   __restrict__ deg,            // [N]
    const unsigned short* __restrict__ Wb,    // [256, 256] bf16 [out][in]
    const float* __restrict__ bias,           // [256]
    float*       __restrict__ out)            // [N, 256]
{
    __shared__ unsigned short As[BM * PADK];
    __shared__ unsigned short Bs[D_OUT * PADK];
    __shared__ float inv_s[BM];

    int t = threadIdx.x;
    int m0 = blockIdx.x * BM;

    if (t < BM) {
        int m = m0 + t;
        int c = (m < N_NODES) ? deg[m] : 1;
        inv_s[t] = 1.0f / (float)((c > 1) ? c : 1);
    }
    __syncthreads();

    int wave = t >> 6;        // 0..7
    int lane = t & 63;
    int wm = wave >> 2;       // 0..1  -> m offset wm*64
    int wn = wave & 3;        // 0..3  -> n offset wn*64
    int lrow = lane & 15;
    int kq = lane >> 4;       // 0..3

    float4v acc[4][4];
    #pragma unroll
    for (int i = 0; i < 4; ++i)
        #pragma unroll
        for (int j = 0; j < 4; ++j)
            acc[i][j] = (float4v){0.f, 0.f, 0.f, 0.f};

    // staging coords (A): thread -> (row, kseg)
    int a_row  = t >> 2;          // 0..127
    int a_kseg = (t & 3) * 8;     // 0,8,16,24

    for (int kc = 0; kc < K_DIM / BK; ++kc) {
        int k0 = kc * BK;

        // ---- stage A chunk: fp32 -> bf16, 8 elems/thread ----
        {
            bool is_agg = (k0 >= 128);
            const float* src = is_agg ? agg : x_dst;
            int koff = (is_agg ? k0 - 128 : k0) + a_kseg;
            int grow = m0 + a_row;
            float4 v0 = make_float4(0.f, 0.f, 0.f, 0.f);
            float4 v1 = v0;
            if (grow < N_NODES) {
                const float* p = src + (size_t)grow * D_SRC + koff;
                v0 = *(const float4*)p;
                v1 = *(const float4*)(p + 4);
            }
            if (is_agg) {
                float iv = inv_s[a_row];
                v0.x *= iv; v0.y *= iv; v0.z *= iv; v0.w *= iv;
                v1.x *= iv; v1.y *= iv; v1.z *= iv; v1.w *= iv;
            }
            union { unsigned short s[8]; short8 v; } pk;
            pk.s[0] = f2bf(v0.x); pk.s[1] = f2bf(v0.y);
            pk.s[2] = f2bf(v0.z); pk.s[3] = f2bf(v0.w);
            pk.s[4] = f2bf(v1.x); pk.s[5] = f2bf(v1.y);
            pk.s[6] = f2bf(v1.z); pk.s[7] = f2bf(v1.w);
            *(short8*)&As[a_row * PADK + a_kseg] = pk.v;
        }

        // ---- stage B chunk: bf16 copy, 8 elems/thread x 2 rounds ----
        #pragma unroll
        for (int r = 0; r < 2; ++r) {
            int i = r * 512 + t;
            int row  = i >> 2;          // 0..255
            int kseg = (i & 3) * 8;
            short8 w = *(const short8*)(Wb + (size_t)row * K_DIM + k0 + kseg);
            *(short8*)&Bs[row * PADK + kseg] = w;
        }
        __syncthreads();

        // ---- fragments + MFMA ----
        short8 afrag[4], bfrag[4];
        #pragma unroll
        for (int mf = 0; mf < 4; ++mf)
            afrag[mf] = *(short8*)&As[(wm * 64 + mf * 16 + lrow) * PADK + kq * 8];
        #pragma unroll
        for (int nf = 0; nf < 4; ++nf)
            bfrag[nf] = *(short8*)&Bs[(wn * 64 + nf * 16 + lrow) * PADK + kq * 8];
        #pragma unroll
        for (int mf = 0; mf < 4; ++mf)
            #pragma unroll
            for (int nf = 0; nf < 4; ++nf)
                acc[mf][nf] = __builtin_amdgcn_mfma_f32_16x16x32_bf16(
                    afrag[mf], bfrag[nf], acc[mf][nf], 0, 0, 0);
        __syncthreads();
    }

    // ---- epilogue: bias + relu + store (D layout: col=lane&15, row=kq*4+r) ----
    #pragma unroll
    for (int nf = 0; nf < 4; ++nf) {
        int col = wn * 64 + nf * 16 + lrow;
        float bv = bias[col];
        #pragma unroll
        for (int mf = 0; mf < 4; ++mf) {
            int rbase = m0 + wm * 64 + mf * 16 + kq * 4;
            #pragma unroll
            for (int r = 0; r < 4; ++r) {
                int row = rbase + r;
                if (row < N_NODES)
                    out[(size_t)row * D_OUT + col] = fmaxf(acc[mf][nf][r] + bv, 0.f);
            }
        }
    }
}

extern "C" void kernel_launch(void* const* d_in, const int* in_sizes, int n_in,
                              void* d_out, int out_size, void* d_ws, size_t ws_size,
                              hipStream_t stream) {
    const float* x_src = (const float*)d_in[0];
    const float* x_dst = (const float*)d_in[1];
    const int*   ei    = (const int*)d_in[2];
    const float* W     = (const float*)d_in[3];
    const float* bias  = (const float*)d_in[4];
    float* out = (float*)d_out;

    int n_edges = in_sizes[2] / 2;

    // workspace layout:
    //   deg     : N_NODES int            (zeroed)
    //   ovf_cnt : 1 int + 3 pad          (zeroed)
    //   ovf     : OVF_CAP*2 int
    //   bucket  : N_NODES*CAP int
    //   agg     : N_NODES*128 float
    //   Wb      : 256*256 ushort (bf16)
    int* deg     = (int*)d_ws;
    int* ovf_cnt = deg + N_NODES;
    int* ovf     = ovf_cnt + 4;
    int* bucket  = ovf + OVF_CAP * 2;
    float* agg   = (float*)(bucket + (size_t)N_NODES * CAP);
    unsigned short* Wb = (unsigned short*)(agg + (size_t)N_NODES * D_SRC);

    hipMemsetAsync(d_ws, 0, (N_NODES + 4) * sizeof(int), stream);

    bucket_kernel<<<(n_edges + 255) / 256, 256, 0, stream>>>(
        ei, deg, ovf_cnt, ovf, bucket, n_edges);

    convert_w_kernel<<<(D_OUT * K_DIM / 4 + 255) / 256, 256, 0, stream>>>(W, Wb);

    gather_kernel<<<(N_NODES + 3) / 4, 256, 0, stream>>>(
        x_src, deg, bucket, agg);

    ovf_fixup_kernel<<<OVF_CAP / 8, 256, 0, stream>>>(
        x_src, ovf_cnt, ovf, agg);

    mfma_gemm_kernel<<<(N_NODES + BM - 1) / BM, 512, 0, stream>>>(
        x_dst, agg, deg, Wb, bias, out);
}